// Round 10
// baseline (4454.791 us; speedup 1.0000x reference)
//
#include <hip/hip_runtime.h>
#include <math.h>

#define IN_DIM 8192
#define HID 128
#define NSTEPS 4096

typedef _Float16 f16x8 __attribute__((ext_vector_type(8)));
typedef float f32x4 __attribute__((ext_vector_type(4)));

__device__ __forceinline__ float sigm(float x) { return 1.f / (1.f + __expf(-x)); }
__device__ __forceinline__ float tanh_f(float x) {
    x = fminf(fmaxf(x, -15.f), 15.f);          // avoid inf/inf NaN
    float e = __expf(2.f * x);
    return (e - 1.f) / (e + 1.f);
}

// ---------------------------------------------------------------------------
// Kernel 1: M = W_enc @ W_dec  (128x128), cvec = W_enc@b_dec + b_enc,
//           e1 = W_enc@x0 + b_enc.  Grid: 128 blocks (one per row p), 128 thr.
// ---------------------------------------------------------------------------
__global__ __launch_bounds__(128) void k_precompute_M(
    const float* __restrict__ W_enc, const float* __restrict__ W_dec,
    const float* __restrict__ b_enc, const float* __restrict__ b_dec,
    const float* __restrict__ x0,
    float* __restrict__ M, float* __restrict__ cvec, float* __restrict__ e1)
{
    const int p = blockIdx.x;
    const int t = threadIdx.x;              // 0..127 (= output column q)
    __shared__ float wl[128];
    __shared__ float red[256];
    float m0 = 0.f, m1 = 0.f, m2 = 0.f, m3 = 0.f, cacc = 0.f, eacc = 0.f;
    for (int i0 = 0; i0 < IN_DIM; i0 += 128) {
        float w = W_enc[(size_t)p * IN_DIM + i0 + t];   // coalesced
        cacc = fmaf(w, b_dec[i0 + t], cacc);
        eacc = fmaf(w, x0[i0 + t], eacc);
        wl[t] = w;
        __syncthreads();
#pragma unroll 8
        for (int k = 0; k < 128; k += 4) {              // W_dec reads coalesced in t
            m0 = fmaf(wl[k],     W_dec[(size_t)(i0 + k) * HID + t], m0);
            m1 = fmaf(wl[k + 1], W_dec[(size_t)(i0 + k + 1) * HID + t], m1);
            m2 = fmaf(wl[k + 2], W_dec[(size_t)(i0 + k + 2) * HID + t], m2);
            m3 = fmaf(wl[k + 3], W_dec[(size_t)(i0 + k + 3) * HID + t], m3);
        }
        __syncthreads();
    }
    M[p * HID + t] = (m0 + m1) + (m2 + m3);
    red[t] = cacc; red[128 + t] = eacc;
    __syncthreads();
    for (int s = 64; s > 0; s >>= 1) {
        if (t < s) { red[t] += red[t + s]; red[128 + t] += red[128 + t + s]; }
        __syncthreads();
    }
    if (t == 0) { cvec[p] = red[0] + b_enc[p]; e1[p] = red[128] + b_enc[p]; }
}

// ---------------------------------------------------------------------------
// Kernel 2: G rows 0..383 = W_ih@M, rows 384..767 = W_hh (copy).
//           gb[0..383] = W_ih@cvec + bias, gb[384..767] = 0.
//           ig1 = W_ih@e1 + bias.  Grid: 768 blocks, 128 threads.
// ---------------------------------------------------------------------------
__global__ __launch_bounds__(128) void k_precompute_G(
    const float* __restrict__ W_ih, const float* __restrict__ W_hh,
    const float* __restrict__ bias, const float* __restrict__ M,
    const float* __restrict__ cvec, const float* __restrict__ e1,
    float* __restrict__ G, float* __restrict__ gb, float* __restrict__ ig1)
{
    const int r = blockIdx.x;
    const int q = threadIdx.x;
    if (r >= 384) {
        G[(size_t)r * HID + q] = W_hh[(size_t)(r - 384) * HID + q];
        if (q == 0) gb[r] = 0.f;
        return;
    }
    __shared__ float red[256];
    float a0 = 0.f, a1 = 0.f, a2 = 0.f, a3 = 0.f;
#pragma unroll 8
    for (int k = 0; k < HID; k += 4) {   // W_ih[r][k] scalar-uniform, M coalesced
        a0 = fmaf(W_ih[r * HID + k],     M[(k) * HID + q], a0);
        a1 = fmaf(W_ih[r * HID + k + 1], M[(k + 1) * HID + q], a1);
        a2 = fmaf(W_ih[r * HID + k + 2], M[(k + 2) * HID + q], a2);
        a3 = fmaf(W_ih[r * HID + k + 3], M[(k + 3) * HID + q], a3);
    }
    G[(size_t)r * HID + q] = (a0 + a1) + (a2 + a3);
    float wq = W_ih[r * HID + q];
    red[q] = wq * cvec[q];
    red[128 + q] = wq * e1[q];
    __syncthreads();
    for (int s = 64; s > 0; s >>= 1) {
        if (q < s) { red[q] += red[q + s]; red[128 + q] += red[128 + q + s]; }
        __syncthreads();
    }
    if (q == 0) { gb[r] = red[0] + bias[r]; ig1[r] = red[128] + bias[r]; }
}

// ---------------------------------------------------------------------------
// Kernel 2b: pack G (f32, 768x128) into MFMA A-fragments (f16), 8-wave layout.
// Fragment (w,j,c): wave w (rows 96w..96w+95), tile j=0..5 (rows 96w+16j..+15),
// K-chunk c (k=32c..+31). A-layout for v_mfma_f32_16x16x32_f16: lane l holds
// A[row=l&15][k=8*(l>>4)+i].
// ---------------------------------------------------------------------------
__global__ __launch_bounds__(256) void k_pack(
    const float* __restrict__ G, _Float16* __restrict__ Gp)
{
    int id = blockIdx.x * 256 + threadIdx.x;   // 0..98303
    int i = id & 7;
    int l = (id >> 3) & 63;
    int frag = id >> 9;                        // 0..191 = w*24 + j*4 + c
    int c = frag & 3;
    int j = (frag >> 2) % 6;
    int w = frag / 24;
    int row = 96 * w + 16 * j + (l & 15);
    int k = 32 * c + ((l >> 4) << 3) + i;
    Gp[id] = (_Float16)G[row * HID + k];
}

// ---------------------------------------------------------------------------
// Kernel 3: sequential GRU scan via MFMA. ONE block, 512 threads (8 waves,
// 2/SIMD). R8/R9 budget: MFMA pipe ~770cyc/step (fixed floor), DS ~1100,
// serial gate ~350, 2 barriers. This round: (a) 8 waves halves B-frag DS
// instrs + barrier skew; (b) REDUNDANT GATES: every wave computes all 128
// units (2 adjacent/lane) into its OWN h-buffer -> producer==consumer, no
// 2nd barrier, no serial-gate wait; (c) double-buffered g_lds (step parity)
// makes ONE barrier/step race-free (drift <1 step provable); (d) gb/bias_n/
// ig1 in per-lane regs (gb rows 384+ are 0, skipped). Weights: 24 A-frags =
// 96 AGPR/thread ("+a"-pinned, R8-verified mechanism), ~75 VGPR, 171 <= 256
// budget at launch_bounds(512,2). H stored by wave 0 as coalesced float2.
// ---------------------------------------------------------------------------
#define WF6(F) F(0,0) F(0,1) F(0,2) F(0,3) F(1,0) F(1,1) F(1,2) F(1,3) \
               F(2,0) F(2,1) F(2,2) F(2,3) F(3,0) F(3,1) F(3,2) F(3,3) \
               F(4,0) F(4,1) F(4,2) F(4,3) F(5,0) F(5,1) F(5,2) F(5,3)

__global__ __launch_bounds__(512, 2) void k_recurrence(
    const _Float16* __restrict__ Gp, const float* __restrict__ gb,
    const float* __restrict__ ig1, const float* __restrict__ bias_n,
    float* __restrict__ H)
{
    const int t = threadIdx.x;           // 0..511
    const int l = t & 63;                // lane
    const int w = t >> 6;                // wave 0..7; rows 96w..96w+95
    __shared__ _Float16 h_buf[8][144];   // per-wave private h (288B stride)
    __shared__ float g_lds[2][6 * HID];  // double-buffered by step parity

    // --- stationary weights: 24 MFMA A-fragments -> AGPRs ---
    const f16x8* gpb = (const f16x8*)Gp;
#define DECLW(j,c) f16x8 wf##j##c = gpb[(w * 24 + j * 4 + c) * 64 + l];
    WF6(DECLW)
#undef DECLW
#define PINW(j,c) asm volatile("" : "+a"(wf##j##c));
    WF6(PINW)
#undef PINW

    const int u0 = 2 * l;                // this lane's gate units: u0, u0+1
    // per-lane constants (gb rows 384.. are zero; ig1 includes bias)
    const float2 gbv0 = *(const float2*)&gb[u0];
    const float2 gbv1 = *(const float2*)&gb[HID + u0];
    const float2 gbv2 = *(const float2*)&gb[2 * HID + u0];
    const float2 bnv  = *(const float2*)&bias_n[u0];
    float hp0, hp1;                      // carried h for units u0, u0+1

    // prologue: step 1 from ig1 (h0 = 0 -> hg = 0), redundant in every wave
    {
        const float2 i0 = *(const float2*)&ig1[u0];
        const float2 i1 = *(const float2*)&ig1[HID + u0];
        const float2 i2 = *(const float2*)&ig1[2 * HID + u0];
        float zg0 = sigm(i1.x), zg1 = sigm(i1.y);
        float ng0 = tanh_f(fmaf(sigm(i0.x), bnv.x, i2.x));
        float ng1 = tanh_f(fmaf(sigm(i0.y), bnv.y, i2.y));
        hp0 = ng0 - zg0 * ng0;
        hp1 = ng1 - zg1 * ng1;
        union { _Float16 h[2]; unsigned u; } pk;
        pk.h[0] = (_Float16)hp0; pk.h[1] = (_Float16)hp1;
        *(unsigned*)((char*)&h_buf[w][0] + 4 * l) = pk.u;
        if (w == 0) { float2 st2 = { hp0, hp1 }; *(float2*)&H[u0] = st2; }
    }

    const int g4 = l >> 4;                          // 16-lane group 0..3
    const char* hbase = (const char*)&h_buf[w][0] + g4 * 16;
    const int pbase = 96 * w + (g4 << 2);           // writer row base (j=0)
    const bool writer = (l & 15) == 0;
    const f32x4 zero = {0.f, 0.f, 0.f, 0.f};

    for (int st = 1; st < NSTEPS; ++st) {
        float* gc = g_lds[st & 1];
        // own h written last step (same-wave LDS ordering; explicit for safety)
        asm volatile("s_waitcnt lgkmcnt(0)" ::: "memory");
        // B-fragments: chunk c, lane l -> h[32c + 8*g4 + i]
        f16x8 b0 = *(const f16x8*)(hbase);
        f16x8 b1 = *(const f16x8*)(hbase + 64);
        f16x8 b2 = *(const f16x8*)(hbase + 128);
        f16x8 b3 = *(const f16x8*)(hbase + 192);
        // 6 independent 4-deep MFMA chains (R8-best config)
#define TILE(j) \
        f32x4 d##j = __builtin_amdgcn_mfma_f32_16x16x32_f16(wf##j##0, b0, zero, 0, 0, 0); \
        d##j = __builtin_amdgcn_mfma_f32_16x16x32_f16(wf##j##1, b1, d##j, 0, 0, 0); \
        d##j = __builtin_amdgcn_mfma_f32_16x16x32_f16(wf##j##2, b2, d##j, 0, 0, 0); \
        d##j = __builtin_amdgcn_mfma_f32_16x16x32_f16(wf##j##3, b3, d##j, 0, 0, 0);
        TILE(0) TILE(1) TILE(2) TILE(3) TILE(4) TILE(5)
#undef TILE
        if (writer) {                    // lanes 0,16,32,48: 4 rows per tile
            *(f32x4*)&gc[pbase]      = d0;
            *(f32x4*)&gc[pbase + 16] = d1;
            *(f32x4*)&gc[pbase + 32] = d2;
            *(f32x4*)&gc[pbase + 48] = d3;
            *(f32x4*)&gc[pbase + 64] = d4;
            *(f32x4*)&gc[pbase + 80] = d5;
        }
        __syncthreads();                 // THE single barrier per step
        // gate phase, fully redundant in every wave (2 adjacent units/lane)
        float2 gi  = *(const float2*)&gc[u0];            // ir
        float2 gz  = *(const float2*)&gc[HID + u0];      // iz
        float2 gn  = *(const float2*)&gc[2 * HID + u0];  // in
        float2 ghr = *(const float2*)&gc[3 * HID + u0];  // hr
        float2 ghz = *(const float2*)&gc[4 * HID + u0];  // hz
        float2 ghn = *(const float2*)&gc[5 * HID + u0];  // hn
        float rg0 = sigm(gi.x + gbv0.x + ghr.x);
        float rg1 = sigm(gi.y + gbv0.y + ghr.y);
        float zg0 = sigm(gz.x + gbv1.x + ghz.x);
        float zg1 = sigm(gz.y + gbv1.y + ghz.y);
        float ng0 = tanh_f(gn.x + gbv2.x + rg0 * (ghn.x + bnv.x));
        float ng1 = tanh_f(gn.y + gbv2.y + rg1 * (ghn.y + bnv.y));
        hp0 = ng0 + zg0 * (hp0 - ng0);
        hp1 = ng1 + zg1 * (hp1 - ng1);
        union { _Float16 h[2]; unsigned u; } pk;
        pk.h[0] = (_Float16)hp0; pk.h[1] = (_Float16)hp1;
        *(unsigned*)((char*)&h_buf[w][0] + 4 * l) = pk.u;
        if (w == 0) {                    // coalesced float2 store, never drained
            float2 st2 = { hp0, hp1 };
            *(float2*)&H[(size_t)st * HID + u0] = st2;
        }
    }
}

// ---------------------------------------------------------------------------
// Kernel 4: out[t][i] = dot(H[t][:], W_dec[i][:]) + b_dec[i]
// GEMM M=4096(t) N=8192(i) K=128, fp32 vector. 64x64 tiles, 256 threads,
// 4x4 micro-tile (strided by 16), XOR-swizzled LDS (64KB total, conflict-free).
// ---------------------------------------------------------------------------
__global__ __launch_bounds__(256) void k_decode(
    const float* __restrict__ H, const float* __restrict__ W_dec,
    const float* __restrict__ b_dec, float* __restrict__ out)
{
    __shared__ float4 As[64 * 32];   // [t][k4], k4 XOR-swizzled by (t&7)
    __shared__ float4 Bs[64 * 32];   // [i][k4]
    const int tid = threadIdx.x;
    const int t0 = blockIdx.y * 64;
    const int i0 = blockIdx.x * 64;
#pragma unroll 8
    for (int j = 0; j < 8; ++j) {
        int f = tid + 256 * j;        // 0..2047 float4s, coalesced
        int t = f >> 5;
        int k4 = f & 31;
        int sw = k4 ^ (t & 7);
        As[t * 32 + sw] = *(const float4*)(H + (size_t)(t0 + t) * HID + 4 * k4);
        Bs[t * 32 + sw] = *(const float4*)(W_dec + (size_t)(i0 + t) * HID + 4 * k4);
    }
    __syncthreads();
    const int tx = tid & 15, ty = tid >> 4;
    const int xa = ty & 7, xb = tx & 7;
    float acc[4][4] = {{0.f}};
#pragma unroll 8
    for (int k4 = 0; k4 < 32; ++k4) {
        float4 a[4], b[4];
        int ia = k4 ^ xa, ib = k4 ^ xb;
#pragma unroll
        for (int u = 0; u < 4; ++u) a[u] = As[(ty + 16 * u) * 32 + ia];
#pragma unroll
        for (int v = 0; v < 4; ++v) b[v] = Bs[(tx + 16 * v) * 32 + ib];
#pragma unroll
        for (int u = 0; u < 4; ++u)
#pragma unroll
            for (int v = 0; v < 4; ++v) {
                acc[u][v] = fmaf(a[u].x, b[v].x, acc[u][v]);
                acc[u][v] = fmaf(a[u].y, b[v].y, acc[u][v]);
                acc[u][v] = fmaf(a[u].z, b[v].z, acc[u][v]);
                acc[u][v] = fmaf(a[u].w, b[v].w, acc[u][v]);
            }
    }
#pragma unroll
    for (int u = 0; u < 4; ++u) {
        int t = t0 + ty + 16 * u;
#pragma unroll
        for (int v = 0; v < 4; ++v) {
            int i = i0 + tx + 16 * v;
            out[(size_t)t * IN_DIM + i] = acc[u][v] + b_dec[i];
        }
    }
}

// ---------------------------------------------------------------------------
extern "C" void kernel_launch(void* const* d_in, const int* in_sizes, int n_in,
                              void* d_out, int out_size, void* d_ws, size_t ws_size,
                              hipStream_t stream)
{
    const float* x0     = (const float*)d_in[0];
    const float* W_enc  = (const float*)d_in[1];
    const float* b_enc  = (const float*)d_in[2];
    const float* W_ih   = (const float*)d_in[3];
    const float* W_hh   = (const float*)d_in[4];
    const float* bias   = (const float*)d_in[5];
    const float* bias_n = (const float*)d_in[6];
    const float* W_dec  = (const float*)d_in[7];
    const float* b_dec  = (const float*)d_in[8];
    float* out = (float*)d_out;

    // workspace layout (floats): ~2.76 MB
    float* ws   = (float*)d_ws;
    float* M    = ws;                 // 16384
    float* cvec = ws + 16384;         // 128
    float* e1   = ws + 16512;         // 128
    float* ig1  = ws + 16640;         // 384
    float* gb   = ws + 17024;         // 768
    float* G    = ws + 17792;         // 98304   (16B-aligned)
    float* H    = ws + 116096;        // 524288  (16B-aligned)
    _Float16* Gp = (_Float16*)(ws + 640384);   // 98304 f16 (192 KB)

    k_precompute_M<<<128, 128, 0, stream>>>(W_enc, W_dec, b_enc, b_dec, x0, M, cvec, e1);
    k_precompute_G<<<768, 128, 0, stream>>>(W_ih, W_hh, bias, M, cvec, e1, G, gb, ig1);
    k_pack<<<384, 256, 0, stream>>>(G, Gp);
    k_recurrence<<<1, 512, 0, stream>>>(Gp, gb, ig1, bias_n, H);
    dim3 grid(IN_DIM / 64, NSTEPS / 64);
    k_decode<<<grid, 256, 0, stream>>>(H, W_dec, b_dec, out);
}